// Round 4
// baseline (324.300 us; speedup 1.0000x reference)
//
#include <hip/hip_runtime.h>
#include <math.h>

// out = relu( tile(pool2(x1),2) + tile(pool4(x2),4) + tile(pool8(x3),8)
//             + tile(pool16(x4),16) + ff )   all NCHW fp32, B=16, out 16x256x24x24.
//
// Round-4: single dispatch (no ws; round-2's cross-dispatch pipeline diverged
// under graph replay). vs round-3 (116us, 1.6TB/s, occ 27%, VGPR 32 ->
// latency-bound): (1) block = (b, oh, col-QUARTER) -> 1536 blocks = 6/CU =
// 24 waves/CU; (2) flattened 1536-lane-task pool space, 6 iters x 256 thr,
// phase boundaries 64-aligned (wave-uniform branches), so loads from all four
// inputs overlap; (3) each task batches its float4 loads into a register
// array before reducing (independent loads -> ~8 outstanding per wave).

namespace {

__device__ __forceinline__ float fmax4(const float4 v) {
  return fmaxf(fmaxf(v.x, v.y), fmaxf(v.z, v.w));
}
__device__ __forceinline__ float4 ld4(const float* p) {
  return *reinterpret_cast<const float4*>(p);
}

__global__ __launch_bounds__(256) void fused_block(const float* __restrict__ x1,
                                                   const float* __restrict__ x2,
                                                   const float* __restrict__ x3,
                                                   const float* __restrict__ x4,
                                                   const float* __restrict__ ff,
                                                   float* __restrict__ out) {
  __shared__ __attribute__((aligned(16))) float s1[128 * 6];
  __shared__ __attribute__((aligned(16))) float s2[64 * 6];
  __shared__ __attribute__((aligned(16))) float s3[32 * 6];
  __shared__ __attribute__((aligned(16))) float s4[16 * 6];

  const int blk = blockIdx.x;      // 0..1535
  const int b   = blk / 96;
  const int rem = blk % 96;
  const int oh  = rem >> 2;        // 0..23
  const int q4  = rem & 3;         // output cols q4*6 .. q4*6+5
  const int tid = threadIdx.x;

  // Pool task space: [0,384) A, [384,768) B, [768,1152) C, [1152,1536) D.
  // All boundaries 64-aligned -> wave-uniform branching.
#pragma unroll
  for (int it = 0; it < 6; ++it) {
    const int t = it * 256 + tid;
    if (t < 384) {
      // ---- A: x1 [16,128,48,48], K=2. task = ch(128) x pid(3). One float4
      //      covers 2 windows; 2 row loads. ----
      const int ch = t / 3, pid = t % 3;
      const float* p = x1 + (size_t)(b * 128 + ch) * 2304 + oh * 2 * 48 + q4 * 12 + pid * 4;
      float4 v[2];
      v[0] = ld4(p);
      v[1] = ld4(p + 48);
      s1[ch * 6 + pid * 2]     = fmaxf(fmaxf(v[0].x, v[0].y), fmaxf(v[1].x, v[1].y));
      s1[ch * 6 + pid * 2 + 1] = fmaxf(fmaxf(v[0].z, v[0].w), fmaxf(v[1].z, v[1].w));
    } else if (t < 768) {
      // ---- B: x2 [16,64,96,96], K=4. task = ch(64) x ow(6). 4 row loads. ----
      const int u = t - 384;
      const int ch = u / 6, ow = u % 6;
      const float* p = x2 + (size_t)(b * 64 + ch) * 9216 + oh * 4 * 96 + (q4 * 6 + ow) * 4;
      float4 v[4];
#pragma unroll
      for (int r = 0; r < 4; ++r) v[r] = ld4(p + r * 96);
      float m = fmaxf(fmaxf(fmax4(v[0]), fmax4(v[1])), fmaxf(fmax4(v[2]), fmax4(v[3])));
      s2[ch * 6 + ow] = m;
    } else if (t < 1152) {
      // ---- C: x3 [16,32,192,192], K=8. task = ch(32) x ow(6) x hf(2);
      //      2 lanes/window, 8 row loads, shfl reduce. ----
      const int u = t - 768;
      const int ch = u / 12, r2 = u % 12, ow = r2 >> 1, hf = r2 & 1;
      const float* p = x3 + (size_t)(b * 32 + ch) * 36864 + oh * 8 * 192 + (q4 * 6 + ow) * 8 + hf * 4;
      float4 v[8];
#pragma unroll
      for (int r = 0; r < 8; ++r) v[r] = ld4(p + r * 192);
      float m = -INFINITY;
#pragma unroll
      for (int r = 0; r < 8; ++r) m = fmaxf(m, fmax4(v[r]));
      m = fmaxf(m, __shfl_xor(m, 1));
      if (hf == 0) s3[ch * 6 + ow] = m;
    } else {
      // ---- D: x4 [16,16,384,384], K=16. task = ch(16) x ow(6) x qq(4);
      //      4 lanes/window, 16 row loads in two 8-batches, shfl reduce. ----
      const int u = t - 1152;
      const int ch = u / 24, r2 = u % 24, ow = r2 >> 2, qq = r2 & 3;
      const float* p = x4 + (size_t)(b * 16 + ch) * 147456 + oh * 16 * 384 + (q4 * 6 + ow) * 16 + qq * 4;
      float m = -INFINITY;
#pragma unroll
      for (int g = 0; g < 2; ++g) {
        float4 v[8];
#pragma unroll
        for (int r = 0; r < 8; ++r) v[r] = ld4(p + (g * 8 + r) * 384);
#pragma unroll
        for (int r = 0; r < 8; ++r) m = fmaxf(m, fmax4(v[r]));
      }
      m = fmaxf(m, __shfl_xor(m, 1));
      m = fmaxf(m, __shfl_xor(m, 2));
      if (qq == 0) s4[ch * 6 + ow] = m;
    }
  }

  __syncthreads();

  // ---- Combine: task = c(256) x cp(3); float2 over 2 cols. 768 tasks. ----
#pragma unroll
  for (int it = 0; it < 3; ++it) {
    const int e = it * 256 + tid;
    const int c = e / 3, cp = e % 3;
    const float2 a1 = *reinterpret_cast<const float2*>(&s1[(c & 127) * 6 + cp * 2]);
    const float2 a2 = *reinterpret_cast<const float2*>(&s2[(c & 63)  * 6 + cp * 2]);
    const float2 a3 = *reinterpret_cast<const float2*>(&s3[(c & 31)  * 6 + cp * 2]);
    const float2 a4 = *reinterpret_cast<const float2*>(&s4[(c & 15)  * 6 + cp * 2]);
    const size_t o = (size_t)(b * 256 + c) * 576 + oh * 24 + q4 * 6 + cp * 2;
    const float2 f = *reinterpret_cast<const float2*>(ff + o);
    float2 r;
    r.x = fmaxf((((a1.x + a2.x) + a3.x) + a4.x) + f.x, 0.0f);
    r.y = fmaxf((((a1.y + a2.y) + a3.y) + a4.y) + f.y, 0.0f);
    *reinterpret_cast<float2*>(out + o) = r;
  }
}

}  // namespace

extern "C" void kernel_launch(void* const* d_in, const int* in_sizes, int n_in,
                              void* d_out, int out_size, void* d_ws, size_t ws_size,
                              hipStream_t stream) {
  const float* x1 = (const float*)d_in[0];  // [16,128,48,48]
  const float* x2 = (const float*)d_in[1];  // [16,64,96,96]
  const float* x3 = (const float*)d_in[2];  // [16,32,192,192]
  const float* x4 = (const float*)d_in[3];  // [16,16,384,384]
  const float* ff = (const float*)d_in[4];  // [16,256,24,24]
  float* out = (float*)d_out;               // [16,256,24,24]
  (void)d_ws; (void)ws_size; (void)in_sizes; (void)n_in; (void)out_size;

  fused_block<<<1536, 256, 0, stream>>>(x1, x2, x3, x4, ff, out);
}